// Round 10
// baseline (153.097 us; speedup 1.0000x reference)
//
#include <hip/hip_runtime.h>

// NONA: out = softmax(-cdist(x, x_n), axis=1) @ y
//   x[4096,1024] f32, x_n[8192,1024] f32, y[8192,128] f32, log_T unused.
//
// R10 (R9 was phase-serialized: monolithic K-step = 16-read burst then
// 32-MFMA burst; LDS and MFMA pipes alternate instead of overlap ->
// 4.9k cy wall vs 1.5k content. Fix = m201-template phase split):
//  * each K-step (BK=64) = 2 phases (ks=0/1). Phase =
//      sched_barrier; 8 ds_read (this phase frags) ; 3 stage-issues(kk+2);
//      [ph1 only: vmcnt(6)] ; s_barrier ; sched_barrier ; setprio(1);
//      16 MFMA ; setprio(0) ; s_barrier
//    Reads overlap barrier-wait + other waves' MFMA region (T3); counted
//    vmcnt once per K-step (T4); setprio now has role-split to arbitrate (T5).
//  * ledger unchanged from R9 (proven): triple-buffer A(3x32K)+B(3x16K)=144K,
//    stage(kk+2) issued during step kk, vmcnt(6) == "stage(kk+1) landed,
//    newest 6 = stage(kk+2) outstanding". Cross-wave RAW for ph0(kk) reads:
//    vmcnt(6)+barrier at ph1(kk-1). WAR: stage(kk+2)->buf((kk-1)%3), last
//    read ph1(kk-1), >=2 barriers earlier. Tail: vmcnt(0) at ph1(14).
//  * bn epilogue / PV / prep / combine identical to R9.
//
// ws: xb@0 8Mi | xnb@8Mi 16Mi | yT@24Mi 2Mi | xsq@26Mi 16Ki | xnsq +16Ki |
//     Lpart@26Mi+64Ki 256Ki | Opart@27Mi 32Mi  (59Mi total)

#define N_ 4096
#define M_ 8192
#define D_ 1024
#define C_ 128
#define SPLIT 16
#define MCOLS (M_ / SPLIT)    // 512
#define NBN (MCOLS / 128)     // 4

typedef __bf16 bf16;
typedef __attribute__((ext_vector_type(8))) __bf16 bf16x8;
typedef __attribute__((ext_vector_type(4))) __bf16 bf16x4;
typedef __attribute__((ext_vector_type(4))) float f32x4;

__device__ __forceinline__ void async_copy16(const bf16* gp, void* lp) {
  __builtin_amdgcn_global_load_lds(
      (__attribute__((address_space(1))) void*)const_cast<bf16*>(gp),
      (__attribute__((address_space(3))) void*)lp, 16, 0, 0);
}

// 128-B-row tiles (A/B): 16B-granule XOR row&7 (0-conflict, R1-R9)
__device__ __forceinline__ int swz(int row, int gran) {
  return (row << 7) + ((gran ^ (row & 7)) << 4);
}
// 256-B-row tiles (P/V): 16 granules, XOR row&15
__device__ __forceinline__ int swz2(int row, int gran) {
  return (row << 8) + ((gran ^ (row & 15)) << 4);
}

// A [256][64] (32K, 32 chunks of 1K): 2 chunks starting at j0 (2 loads/thread)
__device__ __forceinline__ void stageA_h(const bf16* src, char* lds, int tid, int j0) {
  const int lane = tid & 63, wave = tid >> 6;
#pragma unroll
  for (int j = j0; j < j0 + 2; ++j) {
    const int ch  = j * 8 + wave;
    const int off = ch * 1024 + lane * 16;
    const int row = off >> 7;
    const int gr  = ((off >> 4) & 7) ^ (row & 7);
    async_copy16(src + (size_t)row * D_ + gr * 8, lds + ch * 1024);
  }
}
// B [128][64] (16K, 16 chunks): 1 chunk (1 load/thread)
__device__ __forceinline__ void stageB_h(const bf16* src, char* lds, int tid, int j) {
  const int lane = tid & 63, wave = tid >> 6;
  const int ch  = j * 8 + wave;
  const int off = ch * 1024 + lane * 16;
  const int row = off >> 7;
  const int gr  = ((off >> 4) & 7) ^ (row & 7);
  async_copy16(src + (size_t)row * D_ + gr * 8, lds + ch * 1024);
}
__device__ __forceinline__ void stageA(const bf16* src, char* lds, int tid) {
  stageA_h(src, lds, tid, 0); stageA_h(src, lds, tid, 2);
}
__device__ __forceinline__ void stageB(const bf16* src, char* lds, int tid) {
  stageB_h(src, lds, tid, 0); stageB_h(src, lds, tid, 1);
}
// V = yT[128 C][128 xn] (32K, 256-B rows): 4 loads/thread
__device__ __forceinline__ void stageV(const bf16* yT, int colbase, char* lds, int tid) {
  const int lane = tid & 63, wave = tid >> 6;
#pragma unroll
  for (int j = 0; j < 4; ++j) {
    const int ch  = j * 8 + wave;
    const int off = ch * 1024 + lane * 16;
    const int row = off >> 8;
    const int gr  = ((off >> 4) & 15) ^ (row & 15);
    async_copy16(yT + (size_t)row * M_ + colbase + gr * 8, lds + ch * 1024);
  }
}

#define VM6  asm volatile("s_waitcnt vmcnt(6)" ::: "memory")
#define VM0  asm volatile("s_waitcnt vmcnt(0)" ::: "memory")
#define NOOP ((void)0)

// One phase: reads (overlap barrier/other-waves' MFMA) ; stage ; wait ;
// barrier ; 16-MFMA cluster ; barrier.
#define PHASE(Ac, Bc, KS, STG, WAIT)                                           \
  {                                                                            \
    __builtin_amdgcn_sched_barrier(0);                                         \
    bf16x8 af[4], bv[4];                                                       \
    _Pragma("unroll") for (int i = 0; i < 4; ++i)                              \
      af[i] = *(const bf16x8*)((Ac) + swz(wr * 64 + i * 16 + c, (KS) * 4 + g));\
    _Pragma("unroll") for (int j = 0; j < 4; ++j)                              \
      bv[j] = *(const bf16x8*)((Bc) + swz(wc * 64 + j * 16 + c, (KS) * 4 + g));\
    STG;                                                                       \
    WAIT;                                                                      \
    __builtin_amdgcn_s_barrier();                                              \
    __builtin_amdgcn_sched_barrier(0);                                         \
    __builtin_amdgcn_s_setprio(1);                                             \
    _Pragma("unroll") for (int j = 0; j < 4; ++j)                              \
    _Pragma("unroll") for (int i = 0; i < 4; ++i)                              \
      Sacc[i][j] = __builtin_amdgcn_mfma_f32_16x16x32_bf16(                    \
          bv[j], af[i], Sacc[i][j], 0, 0, 0);                                  \
    __builtin_amdgcn_s_setprio(0);                                             \
    __builtin_amdgcn_s_barrier();                                              \
  }

// One K-step = 2 phases. DO=1: issue stage(kk+2) split 3+3 across the phases.
#define KSTEP2(Ac, Bc, An, Bn, SA, SB, DO, WAIT1)                              \
  PHASE(Ac, Bc, 0,                                                             \
        if (DO) { stageA_h(SA, An, tid, 0); stageB_h(SB, Bn, tid, 0); }, NOOP) \
  PHASE(Ac, Bc, 1,                                                             \
        if (DO) { stageA_h(SA, An, tid, 2); stageB_h(SB, Bn, tid, 1); }, WAIT1)

__global__ __launch_bounds__(512, 1)
void nona_main(const bf16* __restrict__ xb, const bf16* __restrict__ xnb,
               const bf16* __restrict__ yT, const float* __restrict__ xsq,
               const float* __restrict__ xnsq, float* __restrict__ Opart,
               float* __restrict__ Lpart)
{
  __shared__ __align__(16) char Lds[147456];
  char* const A0 = Lds;             // x-buf kk%3==0; tail: P rows (A0+A1, 64K)
  char* const A1 = Lds + 32768;
  char* const A2 = Lds + 65536;
  char* const B0 = Lds + 98304;     // xn-buf kk%3==0; tail: V (B0+B1, 32K)
  char* const B1 = Lds + 114688;
  char* const B2 = Lds + 131072;
  char* const Pb = A0;              // P [256][128] bf16, 256-B rows
  char* const Vb = B0;              // V [128 C][128 xn]

  const int tid  = threadIdx.x;
  const int lane = tid & 63;
  const int wave = tid >> 6;           // 8 waves: wr = wave&3 (64 rows), wc = wave>>2
  const int wr = wave & 3, wc = wave >> 2;
  const int g = lane >> 4, c = lane & 15;

  const int s    = blockIdx.x & 15;    // split id; bid%8 -> XCD locality
  const int rb   = blockIdx.x >> 4;
  const int row0 = rb * 256;
  const int col0 = s * MCOLS;

  const bf16* xA = xb + (size_t)row0 * D_;

  float xs[4];
#pragma unroll
  for (int rf = 0; rf < 4; ++rf)
    xs[rf] = xsq[row0 + wr * 64 + rf * 16 + c];

  f32x4 Oacc[4][4];
  const f32x4 zero = {0.f, 0.f, 0.f, 0.f};
#pragma unroll
  for (int rf = 0; rf < 4; ++rf)
#pragma unroll
    for (int cc = 0; cc < 4; ++cc) Oacc[rf][cc] = zero;
  float lsum[4] = {0.f, 0.f, 0.f, 0.f};

#pragma unroll 1
  for (int bn = 0; bn < NBN; ++bn) {
    const int colbase = col0 + bn * 128;
    const bf16* xB = xnb + (size_t)colbase * D_;

    f32x4 Sacc[4][4];
#pragma unroll
    for (int rf = 0; rf < 4; ++rf)
#pragma unroll
      for (int cf = 0; cf < 4; ++cf) Sacc[rf][cf] = zero;

    // prologue (prev bn sealed by post-PV syncthreads): stage kk=0,1
    stageA(xA, A0, tid);          stageB(xB, B0, tid);
    stageA(xA + 64, A1, tid);     stageB(xB + 64, B1, tid);
    VM6;                               // stage(0) landed (newest 6 = stage(1))
    __builtin_amdgcn_s_barrier();      // all waves' stage(0) landed

#pragma unroll 1
    for (int t = 0; t < 4; ++t) {      // kk = 3t, 3t+1, 3t+2  (0..11)
      const bf16* sa = xA + (3 * t + 2) * 64;
      const bf16* sb = xB + (3 * t + 2) * 64;
      KSTEP2(A0, B0, A2, B2, sa, sb, 1, VM6)
      KSTEP2(A1, B1, A0, B0, sa + 64, sb + 64, 1, VM6)
      KSTEP2(A2, B2, A1, B1, sa + 128, sb + 128, 1, VM6)
    }
    KSTEP2(A0, B0, A2, B2, xA + 14 * 64, xB + 14 * 64, 1, VM6)   // kk=12
    KSTEP2(A1, B1, A0, B0, xA + 15 * 64, xB + 15 * 64, 1, VM6)   // kk=13
    KSTEP2(A2, B2, A0, B0, xA, xB, 0, VM0)                       // kk=14 (drain)
    KSTEP2(A0, B0, A1, B1, xA, xB, 0, NOOP)                      // kk=15
    __syncthreads();                   // seal kk15 readers (A0/B0) for P/V reuse

    stageV(yT, colbase, Vb, tid);      // V -> B0+B1 (in flight under exp)

    // exp: w = exp(-sqrt(max(xsq + xnsq - 2*dot, 0))); lane holds
    // S[xn = wc*64 + cf*16 + g*4 + r][xrow = wr*64 + rf*16 + c]
#pragma unroll
    for (int cf = 0; cf < 4; ++cf) {
      const float4 nsq4 = *(const float4*)(xnsq + colbase + wc * 64 + cf * 16 + g * 4);
#pragma unroll
      for (int rf = 0; rf < 4; ++rf)
#pragma unroll
        for (int r = 0; r < 4; ++r) {
          float d2 = xs[rf] + ((const float*)&nsq4)[r] - 2.0f * Sacc[rf][cf][r];
          d2 = fmaxf(d2, 0.0f);
          const float wv = __expf(-sqrtf(d2));
          lsum[rf] += wv;
          Sacc[rf][cf][r] = wv;
        }
    }

    // P-write -> A0+A1 [256 xrow][128 xn], b64 per (rf,cf)
#pragma unroll
    for (int rf = 0; rf < 4; ++rf)
#pragma unroll
      for (int cf = 0; cf < 4; ++cf) {
        bf16x4 pk;
#pragma unroll
        for (int r = 0; r < 4; ++r) pk[r] = (bf16)Sacc[rf][cf][r];
        const int row  = wr * 64 + rf * 16 + c;
        const int gran = wc * 8 + cf * 2 + (g >> 1);
        *(bf16x4*)(Pb + (row << 8) + ((gran ^ (row & 15)) << 4) + (g & 1) * 8) = pk;
      }
    __syncthreads();                   // V landed (vmcnt0 drain); P visible

    // PV: O[64 rows x 64 C-half] += P[64 x 128] @ V^T
#pragma unroll
    for (int ks = 0; ks < 4; ++ks) {
      bf16x8 pa[4];
#pragma unroll
      for (int rf = 0; rf < 4; ++rf)
        pa[rf] = *(const bf16x8*)(Pb + swz2(wr * 64 + rf * 16 + c, ks * 4 + g));
      __builtin_amdgcn_s_setprio(1);
#pragma unroll
      for (int cc = 0; cc < 4; ++cc) {
        bf16x8 vb = *(const bf16x8*)(Vb + swz2(wc * 64 + cc * 16 + c, ks * 4 + g));
#pragma unroll
        for (int rf = 0; rf < 4; ++rf)
          Oacc[rf][cc] = __builtin_amdgcn_mfma_f32_16x16x32_bf16(pa[rf], vb, Oacc[rf][cc], 0, 0, 0);
      }
      __builtin_amdgcn_s_setprio(0);
    }
    __syncthreads();                   // seal P/V readers before next bn restage
  }

  // ---- L reduce: over g (shfl), then over wc (LDS) ----
  float* Lr = (float*)Lds;             // [2 wc][256 rows]
#pragma unroll
  for (int rf = 0; rf < 4; ++rf) {
    float v = lsum[rf];
    v += __shfl_xor(v, 16);
    v += __shfl_xor(v, 32);
    if (g == 0) Lr[wc * 256 + wr * 64 + rf * 16 + c] = v;
  }
  __syncthreads();
  if (tid < 256)
    Lpart[(size_t)s * N_ + row0 + tid] = Lr[tid] + Lr[256 + tid];

  float* ob = Opart + ((size_t)s * N_ + row0) * C_;
#pragma unroll
  for (int rf = 0; rf < 4; ++rf)
#pragma unroll
    for (int cc = 0; cc < 4; ++cc)
#pragma unroll
      for (int r = 0; r < 4; ++r)
        ob[(wr * 64 + rf * 16 + g * 4 + r) * C_ + wc * 64 + cc * 16 + c] = Oacc[rf][cc][r];
}

// fused prep: rows [0,N) = x -> xb/xsq; rows [N, N+M) = xn -> xnb/xnsq
__global__ void prep_rows(const float* __restrict__ x, const float* __restrict__ xn,
                          bf16* __restrict__ xb, bf16* __restrict__ xnb,
                          float* __restrict__ xsq, float* __restrict__ xnsq)
{
  const int blk = blockIdx.x;
  const float* src; bf16* dst; float* sq; int row;
  if (blk < N_) { src = x;  dst = xb;  sq = xsq;  row = blk; }
  else          { src = xn; dst = xnb; sq = xnsq; row = blk - N_; }
  const int t = threadIdx.x;                   // 256 threads, 4 f32 each
  const float4 v = reinterpret_cast<const float4*>(src + (size_t)row * D_)[t];
  float ss = v.x * v.x + v.y * v.y + v.z * v.z + v.w * v.w;
  bf16x4 hv;
  hv[0] = (bf16)v.x; hv[1] = (bf16)v.y; hv[2] = (bf16)v.z; hv[3] = (bf16)v.w;
  *reinterpret_cast<bf16x4*>(dst + (size_t)row * D_ + t * 4) = hv;
#pragma unroll
  for (int o = 32; o > 0; o >>= 1) ss += __shfl_down(ss, o);
  __shared__ float red[4];
  if ((t & 63) == 0) red[t >> 6] = ss;
  __syncthreads();
  if (t == 0) sq[row] = red[0] + red[1] + red[2] + red[3];
}

// y[8192][128] f32 -> yT[128][8192] bf16
__global__ void prep_yT(const float* __restrict__ y, bf16* __restrict__ yT)
{
  __shared__ bf16 tile[C_][72];
  const int m0 = blockIdx.x * 64;
  const int t = threadIdx.x;
#pragma unroll
  for (int i = 0; i < 32; ++i) {
    const int idx = i * 256 + t;               // 0..8191
    const int ml = idx >> 7, cc = idx & 127;
    tile[cc][ml] = (bf16)y[(size_t)(m0 + ml) * C_ + cc];
  }
  __syncthreads();
#pragma unroll
  for (int i = 0; i < 32; ++i) {
    const int idx = i * 256 + t;
    const int cc = idx >> 6, ml = idx & 63;
    yT[(size_t)cc * M_ + m0 + ml] = tile[cc][ml];
  }
}

__global__ void combine(const float* __restrict__ Opart, const float* __restrict__ Lpart,
                        float* __restrict__ out)
{
  const int i = blockIdx.x * 256 + threadIdx.x;   // < N_*C_
  const int row = i >> 7;
  float o = 0.f, l = 0.f;
#pragma unroll
  for (int s = 0; s < SPLIT; ++s) {
    o += Opart[(size_t)s * N_ * C_ + i];
    l += Lpart[(size_t)s * N_ + row];
  }
  out[i] = o / l;
}

extern "C" void kernel_launch(void* const* d_in, const int* in_sizes, int n_in,
                              void* d_out, int out_size, void* d_ws, size_t ws_size,
                              hipStream_t stream)
{
  const float* x  = (const float*)d_in[0];
  const float* xn = (const float*)d_in[1];
  const float* y  = (const float*)d_in[2];
  // d_in[3] = log_T: computed-but-unused in the reference forward.
  float* out = (float*)d_out;

  char* ws = (char*)d_ws;
  bf16*  xb    = (bf16*)(ws);
  bf16*  xnb   = (bf16*)(ws + (size_t)8  * 1024 * 1024);
  bf16*  yT    = (bf16*)(ws + (size_t)24 * 1024 * 1024);
  float* xsq   = (float*)(ws + (size_t)26 * 1024 * 1024);
  float* xnsq  = (float*)(ws + (size_t)26 * 1024 * 1024 + 16 * 1024);
  float* Lpart = (float*)(ws + (size_t)26 * 1024 * 1024 + 64 * 1024);
  float* Opart = (float*)(ws + (size_t)27 * 1024 * 1024);   // 16 x 2 MiB

  prep_rows<<<N_ + M_, 256, 0, stream>>>(x, xn, xb, xnb, xsq, xnsq);
  prep_yT<<<M_ / 64, 256, 0, stream>>>(y, yT);
  nona_main<<<16 * SPLIT, 512, 0, stream>>>(xb, xnb, yT, xsq, xnsq, Opart, Lpart);
  combine<<<(N_ * C_) / 256, 256, 0, stream>>>(Opart, Lpart, out);
}